// Round 29
// baseline (88.266 us; speedup 1.0000x reference)
//
#include <hip/hip_runtime.h>
#include <hip/hip_bf16.h>
#include <math.h>

// MultiHeadAttention: B=2, S=2048, D=1024, H=16, HD=64
// Pipeline: fused cvt (+mask->w tables) | QKV GEMM (MFMA bf16, 2-phase dbuf) |
// flash attn.
// Attn (r28 pipeline + V-through-LDS): 512 blocks (128-row Q tiles), 4 waves
// x 32 rows (2 subtiles). Swapped-QK, P^T in registers. K AND V staged
// together via global_load_lds (2x16K dbuf, one __syncthreads/iter):
//   KV buf = K 8K (row-major, XOR-swizzled) | V 8K (frag order, LO/HI SPLIT:
//   lo region [db][lane][e0..7], hi region [db][lane][e8..15] -> lane-stride
//   16B ds_reads, conflict-free by construction).
// r29 rationale: r13's V-direct made every wave re-read the full 8KB V tile
// from L2 (4x redundant per block, ~512MB chip-wide; r16 measured this exact
// redundancy pattern on K at +12us). Staging V once per block cuts block V
// traffic 4x and vmem instrs/wave-tile 12->6. Deferred exp/PV (one tile
// behind QK) retained -- it now hides the V ds_read latency.

typedef __bf16 bf16_t;
typedef __attribute__((ext_vector_type(8))) __bf16 bf16x8;
typedef __attribute__((ext_vector_type(4))) __bf16 bf16x4;
typedef __attribute__((ext_vector_type(4))) float f32x4;

#define B_  2
#define S_  2048
#define D_  1024
#define H_  16
#define HD_ 64
#define M_  (B_ * S_)   // 4096
#define K_  D_          // 1024
#define NT_ (S_ / 64)   // 32 kv tiles
#define LOG2E 1.44269504f
#define CS_Q (0.125f * LOG2E)   // folded into Q at GEMM epilogue

#if __has_builtin(__builtin_amdgcn_exp2f)
#define EXP2F(x) __builtin_amdgcn_exp2f(x)
#else
#define EXP2F(x) exp2f(x)
#endif

__device__ __forceinline__ f32x4 mfma16x16x32(bf16x8 a, bf16x8 b, f32x4 c) {
    return __builtin_amdgcn_mfma_f32_16x16x32_bf16(a, b, c, 0, 0, 0);
}

__device__ __forceinline__ void gload_lds16(const bf16_t* g, bf16_t* l) {
    __builtin_amdgcn_global_load_lds(
        (const __attribute__((address_space(1))) void*)g,
        (__attribute__((address_space(3))) void*)l,
        16, 0, 0);
}

// ---------------------------------------------------------------- conversion
// Segments: X (1,048,576 f4) | Wq | Wk | Wv (262,144 f4 each) | mask (1024 f4).
// Mask -> w = e^mask: f32 table wfp[B][S] (folded into V at GEMM epilogue)
// and bf16 B-fragment table wfb[B][32 t][4 kg][16 e] (denominator MFMA).
__global__ void cvt_all(const float* __restrict__ hs, const float* __restrict__ wq,
                        const float* __restrict__ wk, const float* __restrict__ wv,
                        const float* __restrict__ mask,
                        bf16_t* __restrict__ Xb, bf16_t* __restrict__ Wb3,
                        float* __restrict__ wfp, bf16_t* __restrict__ wfb) {
    const int i = blockIdx.x * blockDim.x + threadIdx.x;
    if (i >= 1835008) {                     // mask segment (block-aligned tail)
        const int off = i - 1835008;
        if (off < 1024) {
            float4 v = ((const float4*)mask)[off];
            float4 w4;
            w4.x = exp2f(v.x * LOG2E); w4.y = exp2f(v.y * LOG2E);
            w4.z = exp2f(v.z * LOG2E); w4.w = exp2f(v.w * LOG2E);
            ((float4*)wfp)[off] = w4;
            // bf16 fragment table: k = t*64 + nb*16 + kg*4 + j, e = nb*4 + j
            const int k4 = off * 4;
            const int bb = k4 >> 11, k = k4 & 2047;
            const int t  = k >> 6,  kt = k & 63;
            const int nb = kt >> 4, kgf = (kt >> 2) & 3;   // j = 0..3
            bf16x4 wb4;
            wb4[0] = (bf16_t)w4.x; wb4[1] = (bf16_t)w4.y;
            wb4[2] = (bf16_t)w4.z; wb4[3] = (bf16_t)w4.w;
            *(bf16x4*)&wfb[(((size_t)bb * 32 + t) * 4 + kgf) * 16 + nb * 4] = wb4;
        }
        return;
    }
    const float* src; bf16_t* dst; int off;
    if (i < 1048576)      { src = hs; dst = Xb;            off = i; }
    else if (i < 1310720) { src = wq; dst = Wb3;           off = i - 1048576; }
    else if (i < 1572864) { src = wk; dst = Wb3 + 1048576; off = i - 1310720; }
    else                  { src = wv; dst = Wb3 + 2097152; off = i - 1572864; }
    float4 v = ((const float4*)src)[off];
    bf16x4 o;
    o[0] = (bf16_t)v.x; o[1] = (bf16_t)v.y;
    o[2] = (bf16_t)v.z; o[3] = (bf16_t)v.w;
    ((bf16x4*)dst)[off] = o;
}

// ---------------------------------------------------------------- QKV GEMM
// z=0 -> Q [B][H][S][HD], PRE-SCALED by CS_Q (0.125*log2e)
// z=1 -> K [B][H][S][HD]
// z=2 -> V' in MFMA-B-fragment order, W-FOLDED: V'[k][d] = (V[k][d])*w[b][k].
//        Vfrag[bh][t][db][lane=kg*16+lq][e=nb*4+j], k = t*64+nb*16+kg*4+j,
//        d = db*16+lq.
// 2-phase LDS double-buffer: stage(k+1) issued before compute(k), one barrier.
__global__ __launch_bounds__(256, 4)
void gemm_qkv(const bf16_t* __restrict__ Xb, const bf16_t* __restrict__ Wb3,
              const float* __restrict__ bq, const float* __restrict__ bk,
              const float* __restrict__ bv,
              const float* __restrict__ wfp,
              bf16_t* __restrict__ Qo, bf16_t* __restrict__ Ko,
              bf16_t* __restrict__ Vf) {
    __shared__ bf16_t smem[2][8192];        // dbuf: A 128x32 | B 128x32 per buf
    const int z = blockIdx.z;
    const bf16_t* Wb = Wb3 + (size_t)z * (D_ * K_);
    const float* bias = (z == 0) ? bq : (z == 1) ? bk : bv;

    const int tid  = threadIdx.x;
    const int lane = tid & 63;
    const int w    = tid >> 6;
    const int wr   = w >> 1, wc = w & 1;
    const int m0   = blockIdx.y * 128;
    const int n0   = blockIdx.x * 128;

    f32x4 acc[4][4];
    const f32x4 fzero = {0.f, 0.f, 0.f, 0.f};
#pragma unroll
    for (int i = 0; i < 4; i++)
#pragma unroll
        for (int j = 0; j < 4; j++) acc[i][j] = fzero;

    const int koff = (lane >> 4) * 8;

    auto stage = [&](int k0, int buf) {
#pragma unroll
        for (int i = 0; i < 4; i++) {
            const int chunk  = w * 4 + i;
            const int byteoff = chunk * 1024 + lane * 16;
            bf16_t* ldst = &smem[buf][chunk * 512];     // wave-uniform base
            const bf16_t* gsrc;
            if (byteoff < 8192) {                        // A region
                int row = byteoff >> 6;
                int col = (byteoff & 63) >> 1;
                gsrc = Xb + (size_t)(m0 + row) * K_ + k0 + col;
            } else {                                     // B region
                int bo  = byteoff - 8192;
                int row = bo >> 6;
                int col = (bo & 63) >> 1;
                gsrc = Wb + (size_t)(n0 + row) * K_ + k0 + col;
            }
            gload_lds16(gsrc, ldst);
        }
    };

    stage(0, 0);
    __syncthreads();

    for (int kk = 0; kk < K_ / 32; ++kk) {
        const int cur = kk & 1;
        if (kk + 1 < K_ / 32) stage((kk + 1) * 32, cur ^ 1);  // overlaps below

        bf16x8 af[4], bfr[4];
#pragma unroll
        for (int m = 0; m < 4; m++) {
            int row = wr * 64 + m * 16 + (lane & 15);
            af[m] = *(const bf16x8*)&smem[cur][row * 32 + koff];
        }
#pragma unroll
        for (int n = 0; n < 4; n++) {
            int row = wc * 64 + n * 16 + (lane & 15);
            bfr[n] = *(const bf16x8*)&smem[cur][4096 + row * 32 + koff];
        }
#pragma unroll
        for (int m = 0; m < 4; m++)
#pragma unroll
            for (int n = 0; n < 4; n++)
                acc[m][n] = mfma16x16x32(af[m], bfr[n], acc[m][n]);

        // one barrier/iter: publishes stage(kk+1) AND guards buf reuse
        __syncthreads();
    }

#pragma unroll
    for (int m = 0; m < 4; m++) {
        const int gm    = m0 + wr * 64 + m * 16 + ((lane >> 4) << 2);
        const int bidx  = gm >> 11;
        const int sbase = gm & 2047;                    // multiple of 4
#pragma unroll
        for (int n = 0; n < 4; n++) {
            const int gn = n0 + wc * 64 + n * 16 + (lane & 15);
            const int h  = gn >> 6, hd = gn & 63;
            const float bias_v = bias[gn];
            const size_t bh = (size_t)bidx * H_ + h;
            if (z == 2) {
                // fragment-order, w-folded V write: one 8B store
                const int t   = sbase >> 6, k0i = sbase & 63;
                const int nb  = k0i >> 4, kgf = (k0i >> 2) & 3;
                const int db  = hd >> 4,  lqf = hd & 15;
                const float4 w4 = *(const float4*)&wfp[bidx * S_ + sbase];
                bf16x4 pack;
                pack[0] = (bf16_t)((acc[m][n][0] + bias_v) * w4.x);
                pack[1] = (bf16_t)((acc[m][n][1] + bias_v) * w4.y);
                pack[2] = (bf16_t)((acc[m][n][2] + bias_v) * w4.z);
                pack[3] = (bf16_t)((acc[m][n][3] + bias_v) * w4.w);
                bf16_t* dst = Vf + ((bh * 32 + t) * 4 + db) * 1024 +
                    (kgf * 16 + lqf) * 16 + nb * 4;
                *(bf16x4*)dst = pack;
            } else if (z == 0) {
#pragma unroll
                for (int j = 0; j < 4; j++) {
                    float y = (acc[m][n][j] + bias_v) * CS_Q;
                    Qo[(bh * S_ + sbase + j) * HD_ + hd] = (bf16_t)y;
                }
            } else {
#pragma unroll
                for (int j = 0; j < 4; j++) {
                    float y = acc[m][n][j] + bias_v;
                    Ko[(bh * S_ + sbase + j) * HD_ + hd] = (bf16_t)y;
                }
            }
        }
    }
}

// ---------------------------------------------------------------- attention
// 1-D grid of 512 (16 qtiles x 32 heads), XCD-aware: xcd = flat&7 owns 4 heads.
// LDS 32K: KV dbuf 2x16K (K 8K swizzled | V 8K lo/hi-split frag order).
// Deferred exp/PV pipeline (one tile behind QK); V read to regs one tile ahead.
__global__ __launch_bounds__(256, 2)
void attn_fwd(const bf16_t* __restrict__ Qb, const bf16_t* __restrict__ Kb,
              const bf16_t* __restrict__ Vf, const bf16_t* __restrict__ Wfb,
              float* __restrict__ out) {
    const int flat = blockIdx.x;
    const int xcd  = flat & 7;
    const int idx  = flat >> 3;            // 0..63
    const int bh   = xcd * 4 + (idx >> 4); // 0..31
    const int qt   = idx & 15;             // 0..15 (128-row tiles)
    const int b    = bh >> 4;
    const int h    = bh & 15;

    const int tid  = threadIdx.x, lane = tid & 63, w = tid >> 6;

    const bf16_t* Qh = Qb + (size_t)bh * S_ * HD_;
    const bf16_t* Kh = Kb + (size_t)bh * S_ * HD_;
    const bf16_t* Vh = Vf + (size_t)bh * 32 * 4096;   // [t][db][lane][16]
    const bf16_t* Wh = Wfb + (size_t)b * 32 * 64;     // [t][kg][16]

    __shared__ char ShBuf[32768];          // 2 x (K 8K | V 8K)

    const int lq   = lane & 15;
    const int kg   = lane >> 4;            // 0..3
    const int koff = kg * 8;
    const int rsub = lane >> 3;            // K staging: row-in-chunk 0..7
    const int csl8 = (lane & 7) * 8;       // K staging: 16B slot -> elements

    // stage K(t) swizzled + V(t) lo/hi-split into buf (16KB, 4 chunks/wave)
    auto stageKV = [&](int t, int buf) {
        bf16_t* base = (bf16_t*)(ShBuf + buf * 16384);
        const int kv0 = t * 64;
        const bf16_t* Vt_ = Vh + (size_t)t * 4096;
#pragma unroll
        for (int i = 0; i < 4; i++) {
            const int c = w * 4 + i;                    // 0..15, wave-uniform
            bf16_t* ldst = base + c * 512;              // 1 KB chunks
            const bf16_t* gsrc;
            if (c < 8) {                                // K rows, pre-swizzled
                const int cel = csl8 ^ (rsub * 8);
                gsrc = Kh + (size_t)(kv0 + c * 8 + rsub) * HD_ + cel;
            } else if (c < 12) {                        // V lo halves: db=c-8
                gsrc = Vt_ + (c - 8) * 1024 + lane * 16;
            } else {                                    // V hi halves: db=c-12
                gsrc = Vt_ + (c - 12) * 1024 + lane * 16 + 8;
            }
            gload_lds16(gsrc, ldst);
        }
    };

    // ---- Q fragments: 2 subtiles of 16 rows (32 rows/wave, block tile 128)
    const int qbase = qt * 128 + w * 32;
    bf16x8 qf0[2], qf1[2];
#pragma unroll
    for (int s = 0; s < 2; s++) {
        const bf16_t* qr = Qh + (size_t)(qbase + s * 16 + lq) * HD_;
        qf0[s] = *(const bf16x8*)(qr + koff);
        qf1[s] = *(const bf16x8*)(qr + 32 + koff);
    }

    const f32x4 fzero = {0.f, 0.f, 0.f, 0.f};
    f32x4 of[2][4];
    f32x4 of_l[2];                          // denominator accumulators
#pragma unroll
    for (int s = 0; s < 2; s++) {
        of_l[s] = fzero;
#pragma unroll
        for (int i = 0; i < 4; i++) of[s][i] = fzero;
    }

    const int rdsw = (lq & 7) << 4;        // K read swizzle: (row&7)<<4 bytes

    // ---- 2-generation V/w rotation: Cur = deferred-PV use, New = this tile
    bf16x8 vLoC[4], vHiC[4], vLoN[4], vHiN[4], wC0, wC1, wN0, wN1;

    stageKV(0, 0);
    __syncthreads();

    f32x4 sc[2][4];                         // loop-carried scores (tile t-1)

    for (int t = 0; t < NT_; ++t) {
        const int cur = t & 1;
        const char* KB = ShBuf + cur * 16384;

        // ---- (1) K-frag ds_reads for tile t (latency hidden by (3))
        bf16x8 kf0[4], kf1[4];
#pragma unroll
        for (int nb = 0; nb < 4; nb++) {
            const char* kr = KB + (nb * 16 + lq) * 128;
            kf0[nb] = *(const bf16x8*)(kr + ((kg * 16) ^ rdsw));
            kf1[nb] = *(const bf16x8*)(kr + ((64 + kg * 16) ^ rdsw));
        }

        // ---- (2) V-frag ds_reads for tile t (conflict-free lane-stride-16B;
        //      consumed NEXT iteration) + w(t) global prefetch
#pragma unroll
        for (int db = 0; db < 4; db++) {
            const char* vlo = KB + 8192 + db * 1024 + lane * 16;
            vLoN[db] = *(const bf16x8*)(vlo);
            vHiN[db] = *(const bf16x8*)(vlo + 4096);
        }
        {
            const bf16_t* wp = Wh + (size_t)t * 64 + kg * 16;
            wN0 = *(const bf16x8*)(wp);
            wN1 = *(const bf16x8*)(wp + 8);
        }

        // ---- (3) deferred exp + PV for tile t-1 (register-only work)
        if (t > 0) {
            bf16x8 pa0[2], pa1[2];
#pragma unroll
            for (int s = 0; s < 2; s++)
#pragma unroll
                for (int nb = 0; nb < 4; nb++)
#pragma unroll
                    for (int j = 0; j < 4; j++) {
                        float p = EXP2F(sc[s][nb][j]);
                        const int e = (nb & 1) * 4 + j;
                        if (nb < 2) pa0[s][e] = (bf16_t)p;
                        else        pa1[s][e] = (bf16_t)p;
                    }
#pragma unroll
            for (int s = 0; s < 2; s++) {
#pragma unroll
                for (int db = 0; db < 4; db++) {
                    of[s][db] = mfma16x16x32(pa0[s], vLoC[db], of[s][db]);
                    of[s][db] = mfma16x16x32(pa1[s], vHiC[db], of[s][db]);
                }
                of_l[s] = mfma16x16x32(pa0[s], wC0, of_l[s]);
                of_l[s] = mfma16x16x32(pa1[s], wC1, of_l[s]);
            }
        }

        // ---- (4) QK for tile t -> loop-carried sc
#pragma unroll
        for (int s = 0; s < 2; s++)
#pragma unroll
            for (int nb = 0; nb < 4; nb++) {
                f32x4 tacc = fzero;
                tacc = mfma16x16x32(kf0[nb], qf0[s], tacc);
                tacc = mfma16x16x32(kf1[nb], qf1[s], tacc);
                sc[s][nb] = tacc;
            }

        // ---- (5) stage K(t+1)+V(t+1) into buf[cur^1]
        if (t + 1 < NT_) stageKV(t + 1, cur ^ 1);

        // ---- (6) one sync per iter: drains vmcnt (stage) + lgkmcnt (ds
        //      reads into vLoN/vHiN) AND guards KV buffer reuse.
        __syncthreads();

        // ---- (7) rotate generations (register renames)
#pragma unroll
        for (int db = 0; db < 4; db++) {
            vLoC[db] = vLoN[db]; vHiC[db] = vHiN[db];
        }
        wC0 = wN0; wC1 = wN1;
    }

    // ---- epilogue: exp + PV for the final tile
    {
        bf16x8 pa0[2], pa1[2];
#pragma unroll
        for (int s = 0; s < 2; s++)
#pragma unroll
            for (int nb = 0; nb < 4; nb++)
#pragma unroll
                for (int j = 0; j < 4; j++) {
                    float p = EXP2F(sc[s][nb][j]);
                    const int e = (nb & 1) * 4 + j;
                    if (nb < 2) pa0[s][e] = (bf16_t)p;
                    else        pa1[s][e] = (bf16_t)p;
                }
#pragma unroll
        for (int s = 0; s < 2; s++) {
#pragma unroll
            for (int db = 0; db < 4; db++) {
                of[s][db] = mfma16x16x32(pa0[s], vLoC[db], of[s][db]);
                of[s][db] = mfma16x16x32(pa1[s], vHiC[db], of[s][db]);
            }
            of_l[s] = mfma16x16x32(pa0[s], wC0, of_l[s]);
            of_l[s] = mfma16x16x32(pa1[s], wC1, of_l[s]);
        }
    }

    // ---- finalize: of_l[s][j] = sum_k P*w at q=kg*4+j, replicated over lq.
#pragma unroll
    for (int s = 0; s < 2; s++) {
        float inv[4];
#pragma unroll
        for (int j = 0; j < 4; j++) inv[j] = 1.0f / of_l[s][j];
#pragma unroll
        for (int db = 0; db < 4; db++) {
            const int d = h * HD_ + db * 16 + lq;
#pragma unroll
            for (int j = 0; j < 4; j++) {
                const int row = qbase + s * 16 + kg * 4 + j;
                out[((size_t)b * S_ + row) * D_ + d] = of[s][db][j] * inv[j];
            }
        }
    }
}

// ---------------------------------------------------------------- launch
extern "C" void kernel_launch(void* const* d_in, const int* in_sizes, int n_in,
                              void* d_out, int out_size, void* d_ws, size_t ws_size,
                              hipStream_t stream) {
    const float* hs   = (const float*)d_in[0];
    const float* mask = (const float*)d_in[1];
    const float* Wq   = (const float*)d_in[2];
    const float* bq   = (const float*)d_in[3];
    const float* Wk   = (const float*)d_in[4];
    const float* bk   = (const float*)d_in[5];
    const float* Wv   = (const float*)d_in[6];
    const float* bv   = (const float*)d_in[7];
    float* out = (float*)d_out;

    char* ws = (char*)d_ws;
    bf16_t* Xb  = (bf16_t*)(ws);                    //  8,388,608 B  [4096][1024]
    bf16_t* Wb3 = (bf16_t*)(ws + 8388608);          //  6,291,456 B  3x[1024][1024]
    bf16_t* Qb  = (bf16_t*)(ws + 14680064);         //  8,388,608 B  [B][H][S][HD]
    bf16_t* Kb  = (bf16_t*)(ws + 23068672);         //  8,388,608 B  [B][H][S][HD]
    bf16_t* Vfr = (bf16_t*)(ws + 31457280);         //  8,388,608 B  B-frag order
    float*  wfp = (float*)(ws + 39845888);          //     16,384 B  w = e^mask
    bf16_t* wfb = (bf16_t*)(ws + 39862272);         //      8,192 B  w frag table

    cvt_all<<<7172, 256, 0, stream>>>(hs, Wq, Wk, Wv, mask, Xb, Wb3, wfp, wfb);

    dim3 ggrid(D_ / 128, M_ / 128, 3);              // (8, 32, 3)
    gemm_qkv<<<ggrid, 256, 0, stream>>>(Xb, Wb3, bq, bk, bv, wfp, Qb, Kb, Vfr);

    attn_fwd<<<512, 256, 0, stream>>>(Qb, Kb, Vfr, wfb, out);
}

// Round 30
// 86.519 us; speedup vs baseline: 1.0202x; 1.0202x over previous
//
#include <hip/hip_runtime.h>
#include <hip/hip_bf16.h>
#include <math.h>

// MultiHeadAttention: B=2, S=2048, D=1024, H=16, HD=64
// FINAL (r28 config, best measured 86.5us total; 3.3x over first baseline).
// Pipeline: fused cvt (+mask->w tables) | QKV GEMM (MFMA bf16, 2-phase dbuf) |
// flash attn.
// Attn: 512 blocks (128-row Q tiles), 4 waves x 32 rows (2 subtiles).
// Swapped-QK, P^T in registers. K staged via global_load_lds (2-phase dbuf,
// one __syncthreads/iter; LDS 16K). V'/w register-prefetched (3-deep
// rotation). QK C-in = 0. Denominator via w-fragment MFMA. Bare v_exp_f32.
// exp+PV run one tile behind QK (deferred pipeline).
// Ledger: occupancy x2/x4, zero-sync, sync-reorder, unroll ctl, phase-batch,
// LDS-V all neutral-or-worse; wins were V/w reg-prefetch (+25%), arithmetic
// offload to MFMA (+20%), staged-K dbuf (+2.3x), swapped-QK P-in-regs (+7%).

typedef __bf16 bf16_t;
typedef __attribute__((ext_vector_type(8))) __bf16 bf16x8;
typedef __attribute__((ext_vector_type(4))) __bf16 bf16x4;
typedef __attribute__((ext_vector_type(4))) float f32x4;

#define B_  2
#define S_  2048
#define D_  1024
#define H_  16
#define HD_ 64
#define M_  (B_ * S_)   // 4096
#define K_  D_          // 1024
#define NT_ (S_ / 64)   // 32 kv tiles
#define LOG2E 1.44269504f
#define CS_Q (0.125f * LOG2E)   // folded into Q at GEMM epilogue

#if __has_builtin(__builtin_amdgcn_exp2f)
#define EXP2F(x) __builtin_amdgcn_exp2f(x)
#else
#define EXP2F(x) exp2f(x)
#endif

__device__ __forceinline__ f32x4 mfma16x16x32(bf16x8 a, bf16x8 b, f32x4 c) {
    return __builtin_amdgcn_mfma_f32_16x16x32_bf16(a, b, c, 0, 0, 0);
}

__device__ __forceinline__ void gload_lds16(const bf16_t* g, bf16_t* l) {
    __builtin_amdgcn_global_load_lds(
        (const __attribute__((address_space(1))) void*)g,
        (__attribute__((address_space(3))) void*)l,
        16, 0, 0);
}

// ---------------------------------------------------------------- conversion
__global__ void cvt_all(const float* __restrict__ hs, const float* __restrict__ wq,
                        const float* __restrict__ wk, const float* __restrict__ wv,
                        const float* __restrict__ mask,
                        bf16_t* __restrict__ Xb, bf16_t* __restrict__ Wb3,
                        float* __restrict__ wfp, bf16_t* __restrict__ wfb) {
    const int i = blockIdx.x * blockDim.x + threadIdx.x;
    if (i >= 1835008) {                     // mask segment (block-aligned tail)
        const int off = i - 1835008;
        if (off < 1024) {
            float4 v = ((const float4*)mask)[off];
            float4 w4;
            w4.x = exp2f(v.x * LOG2E); w4.y = exp2f(v.y * LOG2E);
            w4.z = exp2f(v.z * LOG2E); w4.w = exp2f(v.w * LOG2E);
            ((float4*)wfp)[off] = w4;
            const int k4 = off * 4;
            const int bb = k4 >> 11, k = k4 & 2047;
            const int t  = k >> 6,  kt = k & 63;
            const int nb = kt >> 4, kgf = (kt >> 2) & 3;
            bf16x4 wb4;
            wb4[0] = (bf16_t)w4.x; wb4[1] = (bf16_t)w4.y;
            wb4[2] = (bf16_t)w4.z; wb4[3] = (bf16_t)w4.w;
            *(bf16x4*)&wfb[(((size_t)bb * 32 + t) * 4 + kgf) * 16 + nb * 4] = wb4;
        }
        return;
    }
    const float* src; bf16_t* dst; int off;
    if (i < 1048576)      { src = hs; dst = Xb;            off = i; }
    else if (i < 1310720) { src = wq; dst = Wb3;           off = i - 1048576; }
    else if (i < 1572864) { src = wk; dst = Wb3 + 1048576; off = i - 1310720; }
    else                  { src = wv; dst = Wb3 + 2097152; off = i - 1572864; }
    float4 v = ((const float4*)src)[off];
    bf16x4 o;
    o[0] = (bf16_t)v.x; o[1] = (bf16_t)v.y;
    o[2] = (bf16_t)v.z; o[3] = (bf16_t)v.w;
    ((bf16x4*)dst)[off] = o;
}

// ---------------------------------------------------------------- QKV GEMM
__global__ __launch_bounds__(256, 4)
void gemm_qkv(const bf16_t* __restrict__ Xb, const bf16_t* __restrict__ Wb3,
              const float* __restrict__ bq, const float* __restrict__ bk,
              const float* __restrict__ bv,
              const float* __restrict__ wfp,
              bf16_t* __restrict__ Qo, bf16_t* __restrict__ Ko,
              bf16_t* __restrict__ Vf) {
    __shared__ bf16_t smem[2][8192];        // dbuf: A 128x32 | B 128x32 per buf
    const int z = blockIdx.z;
    const bf16_t* Wb = Wb3 + (size_t)z * (D_ * K_);
    const float* bias = (z == 0) ? bq : (z == 1) ? bk : bv;

    const int tid  = threadIdx.x;
    const int lane = tid & 63;
    const int w    = tid >> 6;
    const int wr   = w >> 1, wc = w & 1;
    const int m0   = blockIdx.y * 128;
    const int n0   = blockIdx.x * 128;

    f32x4 acc[4][4];
    const f32x4 fzero = {0.f, 0.f, 0.f, 0.f};
#pragma unroll
    for (int i = 0; i < 4; i++)
#pragma unroll
        for (int j = 0; j < 4; j++) acc[i][j] = fzero;

    const int koff = (lane >> 4) * 8;

    auto stage = [&](int k0, int buf) {
#pragma unroll
        for (int i = 0; i < 4; i++) {
            const int chunk  = w * 4 + i;
            const int byteoff = chunk * 1024 + lane * 16;
            bf16_t* ldst = &smem[buf][chunk * 512];     // wave-uniform base
            const bf16_t* gsrc;
            if (byteoff < 8192) {                        // A region
                int row = byteoff >> 6;
                int col = (byteoff & 63) >> 1;
                gsrc = Xb + (size_t)(m0 + row) * K_ + k0 + col;
            } else {                                     // B region
                int bo  = byteoff - 8192;
                int row = bo >> 6;
                int col = (bo & 63) >> 1;
                gsrc = Wb + (size_t)(n0 + row) * K_ + k0 + col;
            }
            gload_lds16(gsrc, ldst);
        }
    };

    stage(0, 0);
    __syncthreads();

    for (int kk = 0; kk < K_ / 32; ++kk) {
        const int cur = kk & 1;
        if (kk + 1 < K_ / 32) stage((kk + 1) * 32, cur ^ 1);  // overlaps below

        bf16x8 af[4], bfr[4];
#pragma unroll
        for (int m = 0; m < 4; m++) {
            int row = wr * 64 + m * 16 + (lane & 15);
            af[m] = *(const bf16x8*)&smem[cur][row * 32 + koff];
        }
#pragma unroll
        for (int n = 0; n < 4; n++) {
            int row = wc * 64 + n * 16 + (lane & 15);
            bfr[n] = *(const bf16x8*)&smem[cur][4096 + row * 32 + koff];
        }
#pragma unroll
        for (int m = 0; m < 4; m++)
#pragma unroll
            for (int n = 0; n < 4; n++)
                acc[m][n] = mfma16x16x32(af[m], bfr[n], acc[m][n]);

        __syncthreads();
    }

#pragma unroll
    for (int m = 0; m < 4; m++) {
        const int gm    = m0 + wr * 64 + m * 16 + ((lane >> 4) << 2);
        const int bidx  = gm >> 11;
        const int sbase = gm & 2047;                    // multiple of 4
#pragma unroll
        for (int n = 0; n < 4; n++) {
            const int gn = n0 + wc * 64 + n * 16 + (lane & 15);
            const int h  = gn >> 6, hd = gn & 63;
            const float bias_v = bias[gn];
            const size_t bh = (size_t)bidx * H_ + h;
            if (z == 2) {
                const int t   = sbase >> 6, k0i = sbase & 63;
                const int nb  = k0i >> 4, kgf = (k0i >> 2) & 3;
                const int db  = hd >> 4,  lqf = hd & 15;
                const float4 w4 = *(const float4*)&wfp[bidx * S_ + sbase];
                bf16x4 pack;
                pack[0] = (bf16_t)((acc[m][n][0] + bias_v) * w4.x);
                pack[1] = (bf16_t)((acc[m][n][1] + bias_v) * w4.y);
                pack[2] = (bf16_t)((acc[m][n][2] + bias_v) * w4.z);
                pack[3] = (bf16_t)((acc[m][n][3] + bias_v) * w4.w);
                bf16_t* dst = Vf + ((bh * 32 + t) * 4 + db) * 1024 +
                    (kgf * 16 + lqf) * 16 + nb * 4;
                *(bf16x4*)dst = pack;
            } else if (z == 0) {
#pragma unroll
                for (int j = 0; j < 4; j++) {
                    float y = (acc[m][n][j] + bias_v) * CS_Q;
                    Qo[(bh * S_ + sbase + j) * HD_ + hd] = (bf16_t)y;
                }
            } else {
#pragma unroll
                for (int j = 0; j < 4; j++) {
                    float y = acc[m][n][j] + bias_v;
                    Ko[(bh * S_ + sbase + j) * HD_ + hd] = (bf16_t)y;
                }
            }
        }
    }
}

// ---------------------------------------------------------------- attention
__global__ __launch_bounds__(256, 2)
void attn_fwd(const bf16_t* __restrict__ Qb, const bf16_t* __restrict__ Kb,
              const bf16_t* __restrict__ Vf, const bf16_t* __restrict__ Wfb,
              float* __restrict__ out) {
    const int flat = blockIdx.x;
    const int xcd  = flat & 7;
    const int idx  = flat >> 3;            // 0..63
    const int bh   = xcd * 4 + (idx >> 4); // 0..31
    const int qt   = idx & 15;             // 0..15 (128-row tiles)
    const int b    = bh >> 4;
    const int h    = bh & 15;

    const int tid  = threadIdx.x, lane = tid & 63, w = tid >> 6;

    const bf16_t* Qh = Qb + (size_t)bh * S_ * HD_;
    const bf16_t* Kh = Kb + (size_t)bh * S_ * HD_;
    const bf16_t* Vh = Vf + (size_t)bh * 32 * 4096;   // [t][db][lane][16]
    const bf16_t* Wh = Wfb + (size_t)b * 32 * 64;     // [t][kg][16]

    __shared__ char ShBuf[16384];          // 2 x K 8K

    const int lq   = lane & 15;
    const int kg   = lane >> 4;            // 0..3
    const int koff = kg * 8;
    const int rsub = lane >> 3;            // staging: row-in-chunk 0..7
    const int csl8 = (lane & 7) * 8;       // staging: 16B slot -> elements

    auto stageK = [&](int kv0, int buf) {
        bf16_t* base = (bf16_t*)(ShBuf + buf * 8192);
#pragma unroll
        for (int i = 0; i < 2; i++) {
            const int c = w * 2 + i;                    // 0..7, wave-uniform
            bf16_t* ldst = base + c * 512;              // 1 KB chunks
            const int cel = csl8 ^ (rsub * 8);          // pre-swizzled source col
            const bf16_t* gsrc = Kh + (size_t)(kv0 + c * 8 + rsub) * HD_ + cel;
            gload_lds16(gsrc, ldst);
        }
    };

    // ---- Q fragments: 2 subtiles of 16 rows (32 rows/wave, block tile 128)
    const int qbase = qt * 128 + w * 32;
    bf16x8 qf0[2], qf1[2];
#pragma unroll
    for (int s = 0; s < 2; s++) {
        const bf16_t* qr = Qh + (size_t)(qbase + s * 16 + lq) * HD_;
        qf0[s] = *(const bf16x8*)(qr + koff);
        qf1[s] = *(const bf16x8*)(qr + 32 + koff);
    }

    const f32x4 fzero = {0.f, 0.f, 0.f, 0.f};
    f32x4 of[2][4];
    f32x4 of_l[2];                          // denominator accumulators
#pragma unroll
    for (int s = 0; s < 2; s++) {
        of_l[s] = fzero;
#pragma unroll
        for (int i = 0; i < 4; i++) of[s][i] = fzero;
    }

    const int rdsw = (lq & 7) << 4;        // K read swizzle: (row&7)<<4 bytes

    bf16x8 wB0, wB1, wC0, wC1, wA0, wA1;
    bf16x8 vLoA[4], vHiA[4], vLoB[4], vHiB[4], vLoC[4], vHiC[4];
    {
        const bf16_t* Vt_ = Vh;
#pragma unroll
        for (int db = 0; db < 4; db++) {
            const bf16_t* vp = Vt_ + db * 1024 + lane * 16;
            vLoB[db] = *(const bf16x8*)(vp);
            vHiB[db] = *(const bf16x8*)(vp + 8);
        }
        wB0 = *(const bf16x8*)(Wh + kg * 16);
        wB1 = *(const bf16x8*)(Wh + kg * 16 + 8);
    }
    stageK(0, 0);
    __syncthreads();

    f32x4 sc[2][4];                         // loop-carried scores (tile t-1)

    for (int t = 0; t < NT_; ++t) {
        const int cur = t & 1;
        const char* KB = ShBuf + cur * 8192;

        // ---- (1) issue K-frag ds_reads for tile t (latency hidden by (2))
        bf16x8 kf0[4], kf1[4];
#pragma unroll
        for (int nb = 0; nb < 4; nb++) {
            const char* kr = KB + (nb * 16 + lq) * 128;
            kf0[nb] = *(const bf16x8*)(kr + ((kg * 16) ^ rdsw));
            kf1[nb] = *(const bf16x8*)(kr + ((64 + kg * 16) ^ rdsw));
        }

        // ---- (2) deferred exp + PV for tile t-1 (register-only work)
        if (t > 0) {
            bf16x8 pa0[2], pa1[2];
#pragma unroll
            for (int s = 0; s < 2; s++)
#pragma unroll
                for (int nb = 0; nb < 4; nb++)
#pragma unroll
                    for (int j = 0; j < 4; j++) {
                        float p = EXP2F(sc[s][nb][j]);
                        const int e = (nb & 1) * 4 + j;
                        if (nb < 2) pa0[s][e] = (bf16_t)p;
                        else        pa1[s][e] = (bf16_t)p;
                    }
#pragma unroll
            for (int s = 0; s < 2; s++) {
#pragma unroll
                for (int db = 0; db < 4; db++) {
                    of[s][db] = mfma16x16x32(pa0[s], vLoA[db], of[s][db]);
                    of[s][db] = mfma16x16x32(pa1[s], vHiA[db], of[s][db]);
                }
                of_l[s] = mfma16x16x32(pa0[s], wA0, of_l[s]);
                of_l[s] = mfma16x16x32(pa1[s], wA1, of_l[s]);
            }
        }

        // ---- (3) QK for tile t -> loop-carried sc
#pragma unroll
        for (int s = 0; s < 2; s++)
#pragma unroll
            for (int nb = 0; nb < 4; nb++) {
                f32x4 tacc = fzero;
                tacc = mfma16x16x32(kf0[nb], qf0[s], tacc);
                tacc = mfma16x16x32(kf1[nb], qf1[s], tacc);
                sc[s][nb] = tacc;
            }

        // ---- (4) prefetch V(t+1)/w(t+1) into vC/wC; stageK(t+1)
        if (t + 1 < NT_) {
            const bf16_t* Vn = Vh + (size_t)(t + 1) * 4096;
#pragma unroll
            for (int db = 0; db < 4; db++) {
                const bf16_t* vp = Vn + db * 1024 + lane * 16;
                vLoC[db] = *(const bf16x8*)(vp);
                vHiC[db] = *(const bf16x8*)(vp + 8);
            }
            const bf16_t* wp = Wh + (size_t)(t + 1) * 64 + kg * 16;
            wC0 = *(const bf16x8*)(wp);
            wC1 = *(const bf16x8*)(wp + 8);
            stageK((t + 1) * 64, cur ^ 1);
        }

        // ---- (5) one sync per iter: vmcnt drain + K buffer reuse guard
        __syncthreads();

        // ---- (6) rotate generations (register renames)
#pragma unroll
        for (int db = 0; db < 4; db++) {
            vLoA[db] = vLoB[db]; vHiA[db] = vHiB[db];
            vLoB[db] = vLoC[db]; vHiB[db] = vHiC[db];
        }
        wA0 = wB0; wA1 = wB1;
        wB0 = wC0; wB1 = wC1;
    }

    // ---- epilogue: exp + PV for the final tile
    {
        bf16x8 pa0[2], pa1[2];
#pragma unroll
        for (int s = 0; s < 2; s++)
#pragma unroll
            for (int nb = 0; nb < 4; nb++)
#pragma unroll
                for (int j = 0; j < 4; j++) {
                    float p = EXP2F(sc[s][nb][j]);
                    const int e = (nb & 1) * 4 + j;
                    if (nb < 2) pa0[s][e] = (bf16_t)p;
                    else        pa1[s][e] = (bf16_t)p;
                }
#pragma unroll
        for (int s = 0; s < 2; s++) {
#pragma unroll
            for (int db = 0; db < 4; db++) {
                of[s][db] = mfma16x16x32(pa0[s], vLoA[db], of[s][db]);
                of[s][db] = mfma16x16x32(pa1[s], vHiA[db], of[s][db]);
            }
            of_l[s] = mfma16x16x32(pa0[s], wA0, of_l[s]);
            of_l[s] = mfma16x16x32(pa1[s], wA1, of_l[s]);
        }
    }

    // ---- finalize: of_l[s][j] = sum_k P*w at q=kg*4+j, replicated over lq.
#pragma unroll
    for (int s = 0; s < 2; s++) {
        float inv[4];
#pragma unroll
        for (int j = 0; j < 4; j++) inv[j] = 1.0f / of_l[s][j];
#pragma unroll
        for (int db = 0; db < 4; db++) {
            const int d = h * HD_ + db * 16 + lq;
#pragma unroll
            for (int j = 0; j < 4; j++) {
                const int row = qbase + s * 16 + kg * 4 + j;
                out[((size_t)b * S_ + row) * D_ + d] = of[s][db][j] * inv[j];
            }
        }
    }
}

// ---------------------------------------------------------------- launch
extern "C" void kernel_launch(void* const* d_in, const int* in_sizes, int n_in,
                              void* d_out, int out_size, void* d_ws, size_t ws_size,
                              hipStream_t stream) {
    const float* hs   = (const float*)d_in[0];
    const float* mask = (const float*)d_in[1];
    const float* Wq   = (const float*)d_in[2];
    const float* bq   = (const float*)d_in[3];
    const float* Wk   = (const float*)d_in[4];
    const float* bk   = (const float*)d_in[5];
    const float* Wv   = (const float*)d_in[6];
    const float* bv   = (const float*)d_in[7];
    float* out = (float*)d_out;

    char* ws = (char*)d_ws;
    bf16_t* Xb  = (bf16_t*)(ws);                    //  8,388,608 B  [4096][1024]
    bf16_t* Wb3 = (bf16_t*)(ws + 8388608);          //  6,291,456 B  3x[1024][1024]
    bf16_t* Qb  = (bf16_t*)(ws + 14680064);         //  8,388,608 B  [B][H][S][HD]
    bf16_t* Kb  = (bf16_t*)(ws + 23068672);         //  8,388,608 B  [B][H][S][HD]
    bf16_t* Vfr = (bf16_t*)(ws + 31457280);         //  8,388,608 B  B-frag order
    float*  wfp = (float*)(ws + 39845888);          //     16,384 B  w = e^mask
    bf16_t* wfb = (bf16_t*)(ws + 39862272);         //      8,192 B  w frag table

    cvt_all<<<7172, 256, 0, stream>>>(hs, Wq, Wk, Wv, mask, Xb, Wb3, wfp, wfb);

    dim3 ggrid(D_ / 128, M_ / 128, 3);              // (8, 32, 3)
    gemm_qkv<<<ggrid, 256, 0, stream>>>(Xb, Wb3, bq, bk, bv, wfp, Qb, Kb, Vfr);

    attn_fwd<<<512, 256, 0, stream>>>(Qb, Kb, Vfr, wfb, out);
}